// Round 1
// baseline (42.036 us; speedup 1.0000x reference)
//
#include <hip/hip_runtime.h>
#include <hip/hip_bf16.h>
#include <stdint.h>

#define DEV __device__ __forceinline__

typedef short s4v __attribute__((ext_vector_type(4)));   // 4 bf16 (bit pattern)
typedef float f4v __attribute__((ext_vector_type(4)));

static constexpr int T = 4096;
static constexpr int BATCH = 4;
static constexpr int MD = 64;
static constexpr int H = 16;
static constexpr int PB = T * H;        // 65536 permuted elements per batch
static constexpr int NCHUNK = 4;        // 4096 / 1024 s-chunks

// ---------------- mfma 16x16x16 bf16 (D = A[16x16k] * B[16kx16] + C) -------
#if __has_builtin(__builtin_amdgcn_mfma_f32_16x16x16bf16_1k)
DEV f4v mfma16(s4v a, s4v b, f4v c) {
    return __builtin_amdgcn_mfma_f32_16x16x16bf16_1k(a, b, c, 0, 0, 0);
}
#elif __has_builtin(__builtin_amdgcn_mfma_f32_16x16x16_bf16)
typedef __bf16 bf4v __attribute__((ext_vector_type(4)));
DEV f4v mfma16(s4v a, s4v b, f4v c) {
    return __builtin_amdgcn_mfma_f32_16x16x16_bf16(__builtin_bit_cast(bf4v, a),
                                                   __builtin_bit_cast(bf4v, b), c, 0, 0, 0);
}
#else
DEV f4v mfma16(s4v a, s4v b, f4v c) {
    asm("v_mfma_f32_16x16x16_bf16 %0, %1, %2, %0" : "+v"(c) : "v"(a), "v"(b));
    return c;
}
#endif

DEV short f2bf(float x) {               // fp32 -> bf16 RNE
    uint32_t u = __builtin_bit_cast(uint32_t, x);
    u += 0x7fffu + ((u >> 16) & 1u);
    return (short)(u >> 16);
}

DEV float ex2(float x) {
#if __has_builtin(__builtin_amdgcn_exp2f)
    return __builtin_amdgcn_exp2f(x);
#else
    return exp2f(x);
#endif
}

// ---------------------------------------------------------------------------
// K1: QKV projection -> permuted bf16 layout.
// Q/K perm: elem(b,t,h) = b*PB + (t>>4)*256 + (h>>2)*64 + (t&15)*4 + (h&3)
// V   perm: elem(b,t,h) = b*PB + (t>>4)*256 + ((t&15)>>2)*64 + h*4 + (t&3)
// One wave per 16-row tile; 4 waves/block; grid 256.
// ---------------------------------------------------------------------------
__global__ __launch_bounds__(256) void k_proj(
    const float* __restrict__ idx,
    const float* __restrict__ Wk, const float* __restrict__ bk,
    const float* __restrict__ Wq, const float* __restrict__ bq,
    const float* __restrict__ Wv, const float* __restrict__ bv,
    short* __restrict__ qp, short* __restrict__ kp, short* __restrict__ vp)
{
    const int w = threadIdx.x >> 6, lane = threadIdx.x & 63;
    const int a = lane & 15, g = lane >> 4;
    const int tile = blockIdx.x * 4 + w;        // 0..1023
    const int b = tile >> 8;
    const int trow0 = (tile & 255) << 4;

    const float* rb = idx + (size_t)(b * T + trow0) * MD;

    s4v xf[4], wqf[4], wkf[4], wvf[4];
#pragma unroll
    for (int kc = 0; kc < 4; ++kc) {
        const int ko = kc * 16 + 4 * g;
        f4v x = *(const f4v*)(rb + a * MD + ko);     // idx[t0+a][ko..ko+3]
        f4v q = *(const f4v*)(Wq + a * MD + ko);     // Wq[a][ko..]
        f4v k = *(const f4v*)(Wk + a * MD + ko);
        f4v v = *(const f4v*)(Wv + a * MD + ko);
        xf[kc]  = s4v{f2bf(x.x), f2bf(x.y), f2bf(x.z), f2bf(x.w)};
        wqf[kc] = s4v{f2bf(q.x), f2bf(q.y), f2bf(q.z), f2bf(q.w)};
        wkf[kc] = s4v{f2bf(k.x), f2bf(k.y), f2bf(k.z), f2bf(k.w)};
        wvf[kc] = s4v{f2bf(v.x), f2bf(v.y), f2bf(v.z), f2bf(v.w)};
    }
    f4v aq = {0.f,0.f,0.f,0.f}, ak = {0.f,0.f,0.f,0.f}, av = {0.f,0.f,0.f,0.f};
#pragma unroll
    for (int kc = 0; kc < 4; ++kc) {
        aq = mfma16(wqf[kc], xf[kc], aq);   // D^T[h][t]: lane t=t0+a, h=4g+r
        ak = mfma16(wkf[kc], xf[kc], ak);
        av = mfma16(xf[kc], wvf[kc], av);   // D[t][h]: lane h=a, t=t0+4g+r
    }
    const int slot = b * PB + (tile & 255) * 256 + g * 64 + a * 4;
    f4v bqv = *(const f4v*)(bq + 4 * g);
    f4v bkv = *(const f4v*)(bk + 4 * g);
    const float bvs = bv[a];
    *(s4v*)(qp + slot) = s4v{f2bf(aq.x + bqv.x), f2bf(aq.y + bqv.y),
                             f2bf(aq.z + bqv.z), f2bf(aq.w + bqv.w)};
    *(s4v*)(kp + slot) = s4v{f2bf(ak.x + bkv.x), f2bf(ak.y + bkv.y),
                             f2bf(ak.z + bkv.z), f2bf(ak.w + bkv.w)};
    *(s4v*)(vp + slot) = s4v{f2bf(av.x + bvs), f2bf(av.y + bvs),
                             f2bf(av.z + bvs), f2bf(av.w + bvs)};
}

// ---------------------------------------------------------------------------
// K2: flash attention partials. Block = 4 waves x 16 queries = 64 queries.
// Grid 1024 = (b:4) x (tb:64) x (chunk:4); invalid (chunk start > tmax) exit.
// No max-subtraction (logits ~N(0,1): exp2 cannot overflow fp32).
// Swapped QK^T: S^T = mfma(Kfrag, Qfrag) -> P regs are directly the PV A-frag.
// ---------------------------------------------------------------------------
__global__ __launch_bounds__(256) void k_attn(
    const short* __restrict__ qp, const short* __restrict__ kp,
    const short* __restrict__ vp,
    float* __restrict__ avU, float* __restrict__ lsum)
{
    const int bx = blockIdx.x;
    const int c = bx & 3, tb = (bx >> 2) & 63, b = bx >> 8;
    const int tmax = tb * 64 + 63;
    const int s_lo = c << 10;
    if (s_lo > tmax) return;
    const int s_hi = min(s_lo + 1024, tmax + 1);

    const int w = threadIdx.x >> 6, lane = threadIdx.x & 63;
    const int a = lane & 15, g = lane >> 4;
    const int t0w = tb * 64 + w * 16;
    const int tq = t0w + a;              // this lane's query row

    __shared__ __align__(16) short lds[2048];   // [0:1024) K perm, [1024:2048) V perm

    const s4v Qf = *(const s4v*)(qp + b * PB + (t0w >> 4) * 256 + g * 64 + a * 4);

    f4v acc = {0.f, 0.f, 0.f, 0.f};
    float lp = 0.f;
    const float CS = 0.36067376022224085f;      // 0.25 * log2(e)

    const int nsub = (s_hi - s_lo + 63) >> 6;
    for (int sub = 0; sub < nsub; ++sub) {
        const int s0 = s_lo + (sub << 6);
        {   // stage 64 s-rows of K and V (2KB each, linear copy)
            const int tt = threadIdx.x;
            const short* src = ((tt & 128) ? vp : kp)
                             + b * PB + (s0 >> 4) * 256 + (tt & 127) * 8;
            *(uint4*)&lds[((tt & 128) ? 1024 : 0) + (tt & 127) * 8] =
                *(const uint4*)src;
        }
        __syncthreads();
        if (s0 <= t0w + 15) {
            const int lim = min(s_hi, t0w + 16) - s0;    // > 0 here
            int ntile = (lim + 15) >> 4;
            if (ntile > 4) ntile = 4;
            for (int ti = 0; ti < ntile; ++ti) {
                const int st0 = s0 + ti * 16;
                const s4v Kf = *(const s4v*)&lds[ti * 256 + g * 64 + a * 4];
                const s4v Vf = *(const s4v*)&lds[1024 + ti * 256 + g * 64 + a * 4];
                f4v S = mfma16(Kf, Qf, f4v{0.f,0.f,0.f,0.f});  // S[r]=(s=st0+4g+r, q=tq)
                f4v p;
#pragma unroll
                for (int r = 0; r < 4; ++r) {
                    const int si = st0 + 4 * g + r;
                    const float e = ex2(S[r] * CS);
                    p[r] = (si <= tq) ? e : 0.f;
                }
                lp += p.x + p.y + p.z + p.w;
                const s4v Pf = s4v{f2bf(p.x), f2bf(p.y), f2bf(p.z), f2bf(p.w)};
                acc = mfma16(Pf, Vf, acc);   // acc[r] = avU(q=t0w+4g+r, h=a)
            }
        }
        __syncthreads();
    }
    if (s_lo > t0w + 15) return;     // no query row of this wave uses chunk c

    lp += __shfl_xor(lp, 16);        // row-sum over the 4 lane groups
    lp += __shfl_xor(lp, 32);

    const int cb = c * 4 + b;
    float* ob = avU + ((size_t)cb * T + t0w) * 16;
#pragma unroll
    for (int r = 0; r < 4; ++r)
        ob[(4 * g + r) * 16 + a] = acc[r];
    if (lane < 16)
        lsum[cb * T + t0w + lane] = lp;
}

// ---------------------------------------------------------------------------
// K3: combine chunk partials, normalize, fused output projection (+bp).
// 65536 threads: row = gid & 16383 (coalesced), d-chunk of 16 = gid >> 14.
// ---------------------------------------------------------------------------
__global__ __launch_bounds__(256) void k_out(
    const float* __restrict__ avU, const float* __restrict__ lsum,
    const float* __restrict__ Wp, const float* __restrict__ bp,
    float* __restrict__ out)
{
    const int gid = blockIdx.x * 256 + threadIdx.x;
    const int row = gid & 16383;
    const int dc = gid >> 14;
    const int b = row >> 12, t = row & 4095;
    const int nch = (t >> 10) + 1;

    float av[16];
#pragma unroll
    for (int h = 0; h < 16; ++h) av[h] = 0.f;
    float l = 0.f;
    for (int c = 0; c < nch; ++c) {
        const int cb = c * 4 + b;
        const float* pa = avU + ((size_t)cb * T + t) * 16;
#pragma unroll
        for (int q4 = 0; q4 < 4; ++q4) {
            f4v x = *(const f4v*)(pa + q4 * 4);
            av[q4 * 4 + 0] += x.x; av[q4 * 4 + 1] += x.y;
            av[q4 * 4 + 2] += x.z; av[q4 * 4 + 3] += x.w;
        }
        l += lsum[cb * T + t];
    }
    const float inv = 1.f / l;

    float* orow = out + (size_t)row * 64 + dc * 16;
#pragma unroll
    for (int j4 = 0; j4 < 4; ++j4) {
        f4v o;
#pragma unroll
        for (int jj = 0; jj < 4; ++jj) {
            const int d = dc * 16 + j4 * 4 + jj;
            const float* wr = Wp + d * 16;
            float s = 0.f;
#pragma unroll
            for (int h = 0; h < 16; ++h) s += av[h] * wr[h];
            o[jj] = bp[d] + s * inv;
        }
        *(f4v*)(orow + j4 * 4) = o;
    }
}

// ---------------------------------------------------------------------------
// ws layout (bytes): qp 512K | kp 512K | vp 512K | avU 4M | lsum 256K  (~5.75MB)
// ---------------------------------------------------------------------------
extern "C" void kernel_launch(void* const* d_in, const int* in_sizes, int n_in,
                              void* d_out, int out_size, void* d_ws, size_t ws_size,
                              hipStream_t stream) {
    const float* idx = (const float*)d_in[0];
    const float* Wk  = (const float*)d_in[1];
    const float* bk  = (const float*)d_in[2];
    const float* Wq  = (const float*)d_in[3];
    const float* bq  = (const float*)d_in[4];
    const float* Wv  = (const float*)d_in[5];
    const float* bv  = (const float*)d_in[6];
    const float* Wp  = (const float*)d_in[7];
    const float* bp  = (const float*)d_in[8];
    float* out = (float*)d_out;

    short* qp = (short*)d_ws;
    short* kp = qp + BATCH * PB;
    short* vp = kp + BATCH * PB;
    float* avU  = (float*)(vp + BATCH * PB);
    float* lsum = avU + (size_t)NCHUNK * BATCH * T * H;

    k_proj<<<256, 256, 0, stream>>>(idx, Wk, bk, Wq, bq, Wv, bv, qp, kp, vp);
    k_attn<<<1024, 256, 0, stream>>>(qp, kp, vp, avU, lsum);
    k_out<<<256, 256, 0, stream>>>(avU, lsum, Wp, bp, out);
}

// Round 3
// 39.429 us; speedup vs baseline: 1.0661x; 1.0661x over previous
//
#include <hip/hip_runtime.h>
#include <hip/hip_bf16.h>
#include <stdint.h>

#define DEV __device__ __forceinline__

typedef short s4v __attribute__((ext_vector_type(4)));   // 4 bf16 (bit pattern)
typedef float f4v __attribute__((ext_vector_type(4)));

static constexpr int T = 4096;
static constexpr int BATCH = 4;
static constexpr int MD = 64;
static constexpr int H = 16;
static constexpr int PB = T * H;        // 65536 permuted elements per batch
static constexpr int NCHUNK = 4;        // 4096 / 1024 s-chunks

// ---------------- mfma 16x16x16 bf16 (D = A[16x16k] * B[16kx16] + C) -------
#if __has_builtin(__builtin_amdgcn_mfma_f32_16x16x16bf16_1k)
DEV f4v mfma16(s4v a, s4v b, f4v c) {
    return __builtin_amdgcn_mfma_f32_16x16x16bf16_1k(a, b, c, 0, 0, 0);
}
#elif __has_builtin(__builtin_amdgcn_mfma_f32_16x16x16_bf16)
typedef __bf16 bf4v __attribute__((ext_vector_type(4)));
DEV f4v mfma16(s4v a, s4v b, f4v c) {
    return __builtin_amdgcn_mfma_f32_16x16x16_bf16(__builtin_bit_cast(bf4v, a),
                                                   __builtin_bit_cast(bf4v, b), c, 0, 0, 0);
}
#else
DEV f4v mfma16(s4v a, s4v b, f4v c) {
    asm("v_mfma_f32_16x16x16_bf16 %0, %1, %2, %0" : "+v"(c) : "v"(a), "v"(b));
    return c;
}
#endif

DEV short f2bf(float x) {               // fp32 -> bf16 RNE
    uint32_t u = __builtin_bit_cast(uint32_t, x);
    u += 0x7fffu + ((u >> 16) & 1u);
    return (short)(u >> 16);
}

DEV float ex2(float x) {
#if __has_builtin(__builtin_amdgcn_exp2f)
    return __builtin_amdgcn_exp2f(x);
#else
    return exp2f(x);
#endif
}

// ---------------------------------------------------------------------------
// K1: QKV projection -> permuted bf16 layout. Q is pre-scaled by 0.25*log2(e)
// so the attention kernel applies exp2 directly to the MFMA output.
// Q/K perm: elem(b,t,h) = b*PB + (t>>4)*256 + (h>>2)*64 + (t&15)*4 + (h&3)
// V   perm: elem(b,t,h) = b*PB + (t>>4)*256 + ((t&15)>>2)*64 + h*4 + (t&3)
// ---------------------------------------------------------------------------
__global__ __launch_bounds__(256) void k_proj(
    const float* __restrict__ idx,
    const float* __restrict__ Wk, const float* __restrict__ bk,
    const float* __restrict__ Wq, const float* __restrict__ bq,
    const float* __restrict__ Wv, const float* __restrict__ bv,
    short* __restrict__ qp, short* __restrict__ kp, short* __restrict__ vp)
{
    const int w = threadIdx.x >> 6, lane = threadIdx.x & 63;
    const int a = lane & 15, g = lane >> 4;
    const int tile = blockIdx.x * 4 + w;        // 0..1023
    const int b = tile >> 8;
    const int trow0 = (tile & 255) << 4;

    const float* rb = idx + (size_t)(b * T + trow0) * MD;

    s4v xf[4], wqf[4], wkf[4], wvf[4];
#pragma unroll
    for (int kc = 0; kc < 4; ++kc) {
        const int ko = kc * 16 + 4 * g;
        f4v x = *(const f4v*)(rb + a * MD + ko);     // idx[t0+a][ko..ko+3]
        f4v q = *(const f4v*)(Wq + a * MD + ko);     // Wq[a][ko..]
        f4v k = *(const f4v*)(Wk + a * MD + ko);
        f4v v = *(const f4v*)(Wv + a * MD + ko);
        xf[kc]  = s4v{f2bf(x.x), f2bf(x.y), f2bf(x.z), f2bf(x.w)};
        wqf[kc] = s4v{f2bf(q.x), f2bf(q.y), f2bf(q.z), f2bf(q.w)};
        wkf[kc] = s4v{f2bf(k.x), f2bf(k.y), f2bf(k.z), f2bf(k.w)};
        wvf[kc] = s4v{f2bf(v.x), f2bf(v.y), f2bf(v.z), f2bf(v.w)};
    }
    f4v aq = {0.f,0.f,0.f,0.f}, ak = {0.f,0.f,0.f,0.f}, av = {0.f,0.f,0.f,0.f};
#pragma unroll
    for (int kc = 0; kc < 4; ++kc) {
        aq = mfma16(wqf[kc], xf[kc], aq);   // D^T[h][t]: lane t=t0+a, h=4g+r
        ak = mfma16(wkf[kc], xf[kc], ak);
        av = mfma16(xf[kc], wvf[kc], av);   // D[t][h]: lane h=a, t=t0+4g+r
    }
    const int slot = b * PB + (tile & 255) * 256 + g * 64 + a * 4;
    f4v bqv = *(const f4v*)(bq + 4 * g);
    f4v bkv = *(const f4v*)(bk + 4 * g);
    const float bvs = bv[a];
    const float CS = 0.36067376022224085f;      // 0.25 * log2(e), folded into Q
    *(s4v*)(qp + slot) = s4v{f2bf((aq.x + bqv.x) * CS), f2bf((aq.y + bqv.y) * CS),
                             f2bf((aq.z + bqv.z) * CS), f2bf((aq.w + bqv.w) * CS)};
    *(s4v*)(kp + slot) = s4v{f2bf(ak.x + bkv.x), f2bf(ak.y + bkv.y),
                             f2bf(ak.z + bkv.z), f2bf(ak.w + bkv.w)};
    *(s4v*)(vp + slot) = s4v{f2bf(av.x + bvs), f2bf(av.y + bvs),
                             f2bf(av.z + bvs), f2bf(av.w + bvs)};
}

// ---------------------------------------------------------------------------
// K2: flash attention partials. Block = 4 waves x 16 queries = 64 queries.
// Grid 1024 = (b:4) x (tb:64) x (chunk:4); invalid (chunk start > tmax) exit.
// Round-3 structure: single LDS buffer, TWO barriers per sub (race-free),
// issue-early global prefetch, fully unrolled 4-tile masked compute,
// f2bf RNE pack for P (round-1-proven).
// ---------------------------------------------------------------------------
__global__ __launch_bounds__(256) void k_attn(
    const short* __restrict__ qp, const short* __restrict__ kp,
    const short* __restrict__ vp,
    float* __restrict__ avU, float* __restrict__ lsum)
{
    const int bx = blockIdx.x;
    const int c = bx & 3, tb = (bx >> 2) & 63, b = bx >> 8;
    const int tmax = tb * 64 + 63;
    const int s_lo = c << 10;
    if (s_lo > tmax) return;
    const int s_hi = min(s_lo + 1024, tmax + 1);

    const int w = threadIdx.x >> 6, lane = threadIdx.x & 63;
    const int a = lane & 15, g = lane >> 4;
    const int t0w = tb * 64 + w * 16;
    const int tq = t0w + a;              // this lane's query row

    __shared__ __align__(16) short lds[2048];   // [0:1024)=K, [1024:2048)=V

    const s4v Qf = *(const s4v*)(qp + b * PB + (t0w >> 4) * 256 + g * 64 + a * 4);

    // staging addresses: thread tt copies 16B; waves 0-1 stage K, 2-3 stage V
    const int tt = threadIdx.x;
    const short* sbase = ((tt & 128) ? vp : kp) + b * PB + (tt & 127) * 8;
    const int ldso = ((tt & 128) ? 1024 : 0) + (tt & 127) * 8;

    f4v acc = {0.f, 0.f, 0.f, 0.f};
    float lp = 0.f;

    const int nsub = (s_hi - s_lo + 63) >> 6;
    // prologue: stage sub 0
    *(uint4*)&lds[ldso] = *(const uint4*)(sbase + s_lo * 16);
    __syncthreads();

    for (int sub = 0; sub < nsub; ++sub) {
        const int s0 = s_lo + (sub << 6);
        const bool do_stage = (sub + 1 < nsub);
        uint4 stg;
        if (do_stage)                                   // issue early
            stg = *(const uint4*)(sbase + (s0 + 64) * 16);

        if (s0 <= t0w + 15) {                           // wave-uniform
            s4v Kf[4], Vf[4];
#pragma unroll
            for (int ti = 0; ti < 4; ++ti) {
                Kf[ti] = *(const s4v*)&lds[ti * 256 + g * 64 + a * 4];
                Vf[ti] = *(const s4v*)&lds[1024 + ti * 256 + g * 64 + a * 4];
            }
#pragma unroll
            for (int ti = 0; ti < 4; ++ti) {
                f4v S = mfma16(Kf[ti], Qf, f4v{0.f,0.f,0.f,0.f});
                const int sb = s0 + ti * 16 + 4 * g;    // S[r]=(s=sb+r, q=tq)
                f4v p;
#pragma unroll
                for (int r = 0; r < 4; ++r) {
                    const float e = ex2(S[r]);
                    p[r] = (sb + r <= tq) ? e : 0.f;
                }
                lp += p.x + p.y + p.z + p.w;
                const s4v Pf = s4v{f2bf(p.x), f2bf(p.y), f2bf(p.z), f2bf(p.w)};
                acc = mfma16(Pf, Vf[ti], acc);   // acc[r] = avU(q=t0w+4g+r, h=a)
            }
        }
        __syncthreads();                                // all reads done
        if (do_stage)
            *(uint4*)&lds[ldso] = stg;                  // write late
        __syncthreads();                                // write visible
    }
    if (s_lo > t0w + 15) return;     // no query row of this wave uses chunk c

    lp += __shfl_xor(lp, 16);        // row-sum over the 4 lane groups
    lp += __shfl_xor(lp, 32);

    const int cb = c * 4 + b;
    float* ob = avU + ((size_t)cb * T + t0w) * 16;
#pragma unroll
    for (int r = 0; r < 4; ++r)
        ob[(4 * g + r) * 16 + a] = acc[r];
    if (lane < 16)
        lsum[cb * T + t0w + lane] = lp;
}

// ---------------------------------------------------------------------------
// K3: combine chunk partials, normalize, fused output projection (+bp).
// 65536 threads: row = gid & 16383 (coalesced), d-chunk of 16 = gid >> 14.
// ---------------------------------------------------------------------------
__global__ __launch_bounds__(256) void k_out(
    const float* __restrict__ avU, const float* __restrict__ lsum,
    const float* __restrict__ Wp, const float* __restrict__ bp,
    float* __restrict__ out)
{
    const int gid = blockIdx.x * 256 + threadIdx.x;
    const int row = gid & 16383;
    const int dc = gid >> 14;
    const int b = row >> 12, t = row & 4095;
    const int nch = (t >> 10) + 1;

    float av[16];
#pragma unroll
    for (int h = 0; h < 16; ++h) av[h] = 0.f;
    float l = 0.f;
    for (int c = 0; c < nch; ++c) {
        const int cb = c * 4 + b;
        const float* pa = avU + ((size_t)cb * T + t) * 16;
#pragma unroll
        for (int q4 = 0; q4 < 4; ++q4) {
            f4v x = *(const f4v*)(pa + q4 * 4);
            av[q4 * 4 + 0] += x.x; av[q4 * 4 + 1] += x.y;
            av[q4 * 4 + 2] += x.z; av[q4 * 4 + 3] += x.w;
        }
        l += lsum[cb * T + t];
    }
    const float inv = 1.f / l;

    float* orow = out + (size_t)row * 64 + dc * 16;
#pragma unroll
    for (int j4 = 0; j4 < 4; ++j4) {
        f4v o;
#pragma unroll
        for (int jj = 0; jj < 4; ++jj) {
            const int d = dc * 16 + j4 * 4 + jj;
            const float* wr = Wp + d * 16;
            float s = 0.f;
#pragma unroll
            for (int h = 0; h < 16; ++h) s += av[h] * wr[h];
            o[jj] = bp[d] + s * inv;
        }
        *(f4v*)(orow + j4 * 4) = o;
    }
}

// ---------------------------------------------------------------------------
// ws layout (bytes): qp 512K | kp 512K | vp 512K | avU 4M | lsum 256K  (~5.75MB)
// ---------------------------------------------------------------------------
extern "C" void kernel_launch(void* const* d_in, const int* in_sizes, int n_in,
                              void* d_out, int out_size, void* d_ws, size_t ws_size,
                              hipStream_t stream) {
    const float* idx = (const float*)d_in[0];
    const float* Wk  = (const float*)d_in[1];
    const float* bk  = (const float*)d_in[2];
    const float* Wq  = (const float*)d_in[3];
    const float* bq  = (const float*)d_in[4];
    const float* Wv  = (const float*)d_in[5];
    const float* bv  = (const float*)d_in[6];
    const float* Wp  = (const float*)d_in[7];
    const float* bp  = (const float*)d_in[8];
    float* out = (float*)d_out;

    short* qp = (short*)d_ws;
    short* kp = qp + BATCH * PB;
    short* vp = kp + BATCH * PB;
    float* avU  = (float*)(vp + BATCH * PB);
    float* lsum = avU + (size_t)NCHUNK * BATCH * T * H;

    k_proj<<<256, 256, 0, stream>>>(idx, Wk, bk, Wq, bq, Wv, bv, qp, kp, vp);
    k_attn<<<1024, 256, 0, stream>>>(qp, kp, vp, avU, lsum);
    k_out<<<256, 256, 0, stream>>>(avU, lsum, Wp, bp, out);
}